// Round 15
// baseline (49.023 us; speedup 1.0000x reference)
//
#include <hip/hip_runtime.h>
#include <hip/hip_bf16.h>
#include <stdint.h>

#define BB 32
#define NN 1024
#define MM 1024
#define DD 256

typedef __attribute__((ext_vector_type(8))) short short8;
typedef __attribute__((ext_vector_type(4))) float floatx4;

__device__ inline unsigned short f2bf(float x) {
    union { __hip_bfloat16 h; unsigned short u; } cv;
    cv.h = __float2bfloat16(x);
    return cv.u;
}
__device__ inline short8 pack8(float4 a, float4 b) {
    short8 o;
    o[0] = f2bf(a.x); o[1] = f2bf(a.y); o[2] = f2bf(a.z); o[3] = f2bf(a.w);
    o[4] = f2bf(b.x); o[5] = f2bf(b.y); o[6] = f2bf(b.z); o[7] = f2bf(b.w);
    return o;
}
// async global->LDS. LDS dest = wave-uniform base; HW adds lane*size.
__device__ inline void async_copy16(void* lds, const void* g) {
    __builtin_amdgcn_global_load_lds(
        (const __attribute__((address_space(1))) unsigned int*)g,
        (__attribute__((address_space(3))) unsigned int*)lds, 16, 0, 0);
}
__device__ inline void async_copy4(void* lds, const void* g) {
    __builtin_amdgcn_global_load_lds(
        (const __attribute__((address_space(1))) unsigned int*)g,
        (__attribute__((address_space(3))) unsigned int*)lds, 4, 0, 0);
}

// ---------------------------------------------------------------------------
// Convert h2 ONLY: fp32 -> bf16 + per-row sum of squares (fp32 exact),
// plus rowmin/colmin init folded in. One wave per TWO rows (32 B/lane).
// ---------------------------------------------------------------------------
__global__ __launch_bounds__(256) void convert_kernel(
        const float* __restrict__ h2, unsigned short* __restrict__ h2b,
        float* __restrict__ sq2, unsigned int* __restrict__ minb) {
    int g = blockIdx.x * 256 + threadIdx.x;
    if (g < 2 * BB * NN) minb[g] = 0x7F800000u;   // +inf

    int wid  = blockIdx.x * 4 + (threadIdx.x >> 6);
    int lane = threadIdx.x & 63;
    int l5   = lane & 31;
    int row  = wid * 2 + (lane >> 5);

    const float4* p = (const float4*)(h2 + (size_t)row * DD) + l5 * 2;
    float4 a = p[0], c = p[1];

    float s = a.x*a.x + a.y*a.y + a.z*a.z + a.w*a.w
            + c.x*c.x + c.y*c.y + c.z*c.z + c.w*c.w;
    #pragma unroll
    for (int off = 16; off; off >>= 1) s += __shfl_xor(s, off, 64);

    *(short8*)((char*)(h2b + (size_t)row * DD) + l5 * 16) = pack8(a, c);
    if (l5 == 0) sq2[row] = s;
}

// ---------------------------------------------------------------------------
// r8-identical A-resident GEMM + fused Hausdorff, with in-kernel A convert.
// Grid (32 b, 8 n-tiles) = 256 blocks, 1/CU. 512 thr = 8 waves (2n x 4m;
// wave tile 64n x 32m). Prologue: h1 fp32 staged in TWO 64 KB halves into
// the BUF0/1 region -> UNIFORM all-thread pack to bf16 PANEL (r8's exact
// swizzled layout) + sq1 by-product -> r8's unconditional af extraction.
// PANEL is then overwritten by ring bufs 2/3 => af FORCED register-resident
// (r8's key property). Main loop/waits/epilogue: r8 verbatim.
// ---------------------------------------------------------------------------
__global__ __launch_bounds__(512, 2) void gemm_kernel(
        const float* __restrict__ h1, const unsigned short* __restrict__ h2b,
        const float* __restrict__ sq2,
        unsigned int* __restrict__ rowmin, unsigned int* __restrict__ colmin) {
    __shared__ __align__(16) char pool[98304];
    // [0,64K): bf16 A PANEL (prologue) -> B-bufs 2,3.
    // [64K,96K): fp32 half staging (64 KB spans 64K..128K? NO: half=64 KB
    //            -> staging uses [64K,96K)+[96K... see STG below)
    #define PANEL (pool)
    #define STG   (pool + 32768)          // fp32 half staging: 64 KB
    #define BUF0  (pool + 65536)
    #define BUF1  (pool + 81920)
    #define BUF2  (pool + 0)
    #define BUF3  (pool + 16384)
    __shared__ __align__(16) float  sq1_s[128];
    __shared__ __align__(16) float  sq2_s[1024];
    __shared__ unsigned int cl_s[1024];

    const int b    = blockIdx.x;       // batch; XCD = b%8
    const int tile = blockIdx.y;       // n-tile 0..7
    const int n0   = tile * 128;

    const int tid  = threadIdx.x;
    const int wave = tid >> 6;         // 0..7
    const int lane = tid & 63;
    const int wn   = (wave >> 2) * 64;     // {0,64}
    const int wm   = (wave & 3) * 32;      // {0,32,64,96}

    const char* Ag = (const char*)(h1 + ((size_t)b * NN + n0) * DD);  // 1KB rows
    const char* Bg = (const char*)(h2b + (size_t)b * MM * DD);        // 512B rows

    const int krow = lane >> 4;   // 0..3
    const int rrow = lane & 15;   // 0..15
    const int rx   = rrow & 7;
    const int lrow = krow * 4;
    const int lcol = rrow;

    // colmin LDS init (plain stores; drained before first use)
    cl_s[tid] = 0x7F800000u; cl_s[tid + 512] = 0x7F800000u;

    // ---- prologue: sq2 -> LDS ----
    #pragma unroll
    for (int t = 0; t < 2; ++t)
        async_copy4((char*)sq2_s + t * 2048 + wave * 256,
                    (const char*)(sq2 + b * MM) + t * 2048 + wave * 256 + lane * 4);

    // ---- A: two 64 KB fp32 halves -> STG -> packed bf16 PANEL + sq1 ----
    // NOTE: STG = pool+32768..+98304 overlaps PANEL rows 64..127? No:
    // PANEL pack of half h writes rows h*64..h*64+63 = bytes h*32K..h*32K+32K.
    // half 0 pack writes [0,32K) while STG holds fp32 at [32K,96K): disjoint.
    // half 1 pack writes [32K,64K) which OVERLAPS STG[32K,96K) low part --
    // pack reads row r from STG+r*1024 = [32K+r*1024, ...); writes to
    // PANEL+(64+r)*512 = [32K+32K... wait: (64+r)*512 = 32768+r*512, read
    // addr = 32768 + r*1024: write offset 32768+r*512 <= read offset
    // 32768+r*1024 for all r>=0, and write (512 B) stays below row r's read
    // region except r=0 (write [32768,33280) vs read [32768,33792) -- SAME
    // ROW read-then-write per thread, but OTHER threads of row 0 read after
    // this thread may write? All row-0 reads happen in the same pack phase
    // as row-0 writes. HAZARD. Fix: pack half 1 in REVERSE row order with a
    // barrier is still racy across waves. SAFE fix: stage half 1 into
    // STG2 = pool + 65536 (32 KB only => half = 32 rows). So use FOUR
    // 32-row quarters staged into [64K,96K), packing into PANEL quarters
    // [q*16K,(q+1)*16K) -- always disjoint from [64K,96K). (r14-proven.)
    #define STGQ (pool + 65536)
    #define STAGE_A(q_)                                                       \
        { _Pragma("unroll")                                                   \
          for (int t = 0; t < 4; ++t) {                                       \
            int rl_ = t * 8 + wave;                                           \
            async_copy16(STGQ + rl_ * 1024,                                   \
                Ag + (size_t)((q_) * 32 + rl_) * 1024                         \
                   + ((lane ^ (rl_ & 7)) << 4)); } }

    #pragma unroll 1
    for (int q = 0; q < 4; ++q) {
        STAGE_A(q);
        asm volatile("s_waitcnt vmcnt(0)" ::: "memory");
        __builtin_amdgcn_s_barrier();
        __builtin_amdgcn_sched_barrier(0);
        // uniform pack: 16 threads/row, 32 floats each -> PANEL + sq1
        {
            int prow = tid >> 4;                    // 0..31
            int s_   = tid & 15;
            int rg   = q * 32 + prow;               // rg&7 == prow&7
            const char* rp = STGQ + prow * 1024;
            float sum = 0.f;
            #pragma unroll
            for (int jj = 0; jj < 2; ++jj) {
                int g0 = s_ * 4 + jj * 2;
                float4 f0 = *(const float4*)(rp + ((g0 ^ (prow & 7)) << 4));
                float4 f1 = *(const float4*)(rp + (((g0 + 1) ^ (prow & 7)) << 4));
                sum += f0.x*f0.x + f0.y*f0.y + f0.z*f0.z + f0.w*f0.w
                     + f1.x*f1.x + f1.y*f1.y + f1.z*f1.z + f1.w*f1.w;
                int ub = s_ * 2 + jj;
                *(short8*)(PANEL + (size_t)rg * 512 + ((ub ^ (rg & 7)) << 4))
                    = pack8(f0, f1);
            }
            sum += __shfl_xor(sum, 1, 64);
            sum += __shfl_xor(sum, 2, 64);
            sum += __shfl_xor(sum, 4, 64);
            sum += __shfl_xor(sum, 8, 64);
            if (s_ == 0) sq1_s[rg] = sum;
        }
        asm volatile("s_waitcnt lgkmcnt(0)" ::: "memory");
        __builtin_amdgcn_sched_barrier(0);
        __builtin_amdgcn_s_barrier();
        __builtin_amdgcn_sched_barrier(0);
    }

    // ---- af extraction: r8-identical, unconditional, all waves ----
    short8 af[4][8];
    #pragma unroll
    for (int i = 0; i < 4; ++i) {
        #pragma unroll
        for (int kq = 0; kq < 8; ++kq) {
            int u = (kq * 4 + krow) ^ rx;
            af[i][kq] = *(const short8*)(PANEL
                        + (size_t)(wn + i * 16 + rrow) * 512 + (u << 4));
        }
    }
    asm volatile("s_waitcnt lgkmcnt(0)" ::: "memory");
    __builtin_amdgcn_sched_barrier(0);
    __builtin_amdgcn_s_barrier();
    __builtin_amdgcn_sched_barrier(0);

    // ---- B ring staging (r8 verbatim): 16 KB chunk = 16 sub-chunks of
    //      1 KB (8 rows x 128 B); 2 copies/thread per stage ----
    const int rl  = lane >> 3;
    const int bcu = (lane & 7) ^ rl;
    #define STAGE(mt_, ks_, BUFP)                                             \
        {                                                                     \
            _Pragma("unroll")                                                 \
            for (int c = 0; c < 2; ++c) {                                     \
                int ch_ = wave * 2 + c;                                       \
                int r_  = ch_ * 8 + rl;                                       \
                async_copy16((char*)(BUFP) + ch_ * 1024,                      \
                             Bg + (size_t)((mt_) * 128 + r_) * 512            \
                                + (size_t)(ks_) * 128 + (bcu << 4));          \
            }                                                                 \
        }

    STAGE(0, 0, BUF0);
    STAGE(0, 1, BUF1);
    STAGE(0, 2, BUF2);

    float rmin[4][4];
    #pragma unroll
    for (int i = 0; i < 4; ++i)
        #pragma unroll
        for (int r = 0; r < 4; ++r) rmin[i][r] = 3.0e38f;

    // ---- main loop: 8 mt x 4 ks; ring = step % 4 (r8 verbatim) ----
    #pragma unroll 1
    for (int mt = 0; mt < 8; ++mt) {
        floatx4 acc[4][2] = {};

        #pragma unroll
        for (int ks = 0; ks < 4; ++ks) {
            if (mt == 7 && ks == 2)      { asm volatile("s_waitcnt vmcnt(2)" ::: "memory"); }
            else if (mt == 7 && ks == 3) { asm volatile("s_waitcnt vmcnt(0)" ::: "memory"); }
            else                         { asm volatile("s_waitcnt vmcnt(4)" ::: "memory"); }
            __builtin_amdgcn_s_barrier();
            __builtin_amdgcn_sched_barrier(0);

            if (ks == 0)          { STAGE(mt,     3, BUF3); }
            else if (mt < 7) {
                if (ks == 1)      { STAGE(mt + 1, 0, BUF0); }
                else if (ks == 2) { STAGE(mt + 1, 1, BUF1); }
                else              { STAGE(mt + 1, 2, BUF2); }
            }

            const char* Bb = (ks == 0) ? BUF0 : (ks == 1) ? BUF1
                           : (ks == 2) ? BUF2 : BUF3;
            __builtin_amdgcn_s_setprio(1);
            #pragma unroll
            for (int kk = 0; kk < 2; ++kk) {
                const int u = ((kk << 2) | krow) ^ rx;
                short8 bfv[2];
                #pragma unroll
                for (int j = 0; j < 2; ++j)
                    bfv[j] = *(const short8*)(Bb
                             + (size_t)(wm + j * 16 + rrow) * 128 + (u << 4));
                #pragma unroll
                for (int i = 0; i < 4; ++i)
                    #pragma unroll
                    for (int j = 0; j < 2; ++j)
                        acc[i][j] = __builtin_amdgcn_mfma_f32_16x16x32_bf16(
                            af[i][ks * 2 + kk], bfv[j], acc[i][j], 0, 0, 0);
            }
            __builtin_amdgcn_s_setprio(0);
        }

        // ---- per-mt epilogue: regs + LDS only (no vmem!) ----
        float s2v0 = sq2_s[mt * 128 + wm + lcol];
        float s2v1 = sq2_s[mt * 128 + wm + 16 + lcol];

        float cmin0 = 3.0e38f, cmin1 = 3.0e38f;
        #pragma unroll
        for (int i = 0; i < 4; ++i) {
            float4 s1q = *(const float4*)(&sq1_s[wn + i * 16 + lrow]);
            #pragma unroll
            for (int r = 0; r < 4; ++r) {
                float s1x = ((const float*)&s1q)[r];
                float d0 = fmaxf(s1x + s2v0 - 2.0f * acc[i][0][r], 0.0f);
                float d1 = fmaxf(s1x + s2v1 - 2.0f * acc[i][1][r], 0.0f);
                rmin[i][r] = fminf(rmin[i][r], fminf(d0, d1));
                cmin0 = fminf(cmin0, d0);
                cmin1 = fminf(cmin1, d1);
            }
        }
        cmin0 = fminf(cmin0, __shfl_xor(cmin0, 16, 64));
        cmin0 = fminf(cmin0, __shfl_xor(cmin0, 32, 64));
        cmin1 = fminf(cmin1, __shfl_xor(cmin1, 16, 64));
        cmin1 = fminf(cmin1, __shfl_xor(cmin1, 32, 64));
        if (lane < 16) {
            atomicMin(&cl_s[mt * 128 + wm + lcol],      __float_as_uint(cmin0));
            atomicMin(&cl_s[mt * 128 + wm + 16 + lcol], __float_as_uint(cmin1));
        }
    }

    // ---- final rowmin (global atomics, out of loop) ----
    unsigned int* rm = rowmin + b * NN + n0;
    #pragma unroll
    for (int i = 0; i < 4; ++i) {
        #pragma unroll
        for (int r = 0; r < 4; ++r) {
            float v = rmin[i][r];
            #pragma unroll
            for (int off = 1; off < 16; off <<= 1)
                v = fminf(v, __shfl_xor(v, off, 64));
            if (lcol == 0)
                atomicMin(&rm[wn + i * 16 + lrow + r], __float_as_uint(v));
        }
    }

    // ---- colmin flush: LDS -> global (once) ----
    __syncthreads();
    unsigned int* cmg = colmin + b * MM;
    atomicMin(&cmg[tid],       cl_s[tid]);
    atomicMin(&cmg[tid + 512], cl_s[tid + 512]);
    #undef STAGE
    #undef STAGE_A
    #undef PANEL
    #undef STG
    #undef STGQ
    #undef BUF0
    #undef BUF1
    #undef BUF2
    #undef BUF3
}

// ---------------------------------------------------------------------------
__global__ __launch_bounds__(256) void finalize_kernel(
        const unsigned int* __restrict__ rowmin,
        const unsigned int* __restrict__ colmin,
        float* __restrict__ out) {
    int b = blockIdx.x;
    int tid = threadIdx.x;
    float s = 0.0f;
    for (int i = tid; i < NN; i += 256) s += __uint_as_float(rowmin[b * NN + i]);
    for (int i = tid; i < MM; i += 256) s += __uint_as_float(colmin[b * MM + i]);
    #pragma unroll
    for (int off = 32; off; off >>= 1) s += __shfl_xor(s, off, 64);
    __shared__ float wsum[4];
    if ((tid & 63) == 0) wsum[tid >> 6] = s;
    __syncthreads();
    if (tid == 0) out[b] = (wsum[0] + wsum[1] + wsum[2] + wsum[3]) * (1.0f / 1024.0f);
}

// ---------------------------------------------------------------------------
extern "C" void kernel_launch(void* const* d_in, const int* in_sizes, int n_in,
                              void* d_out, int out_size, void* d_ws, size_t ws_size,
                              hipStream_t stream) {
    const float* h1 = (const float*)d_in[0];
    const float* h2 = (const float*)d_in[1];
    float* out = (float*)d_out;

    char* ws = (char*)d_ws;
    unsigned short* h2b = (unsigned short*)ws;                    // 16 MB
    float* sq2          = (float*)(ws + (size_t)BB * MM * DD * 2);
    unsigned int* rowmin = (unsigned int*)(sq2 + BB * MM);        // 128 KB
    unsigned int* colmin = rowmin + BB * NN;                      // 128 KB

    // h2 convert + norms + min-buffer init (rowmin/colmin contiguous)
    hipLaunchKernelGGL(convert_kernel, dim3(4096), dim3(256), 0, stream,
                       h2, h2b, sq2, rowmin);

    hipLaunchKernelGGL(gemm_kernel, dim3(BB, 8), dim3(512), 0, stream,
                       h1, h2b, sq2, rowmin, colmin);

    hipLaunchKernelGGL(finalize_kernel, dim3(BB), dim3(256), 0, stream,
                       rowmin, colmin, out);
}

// Round 16
// 49.006 us; speedup vs baseline: 1.0003x; 1.0003x over previous
//
#include <hip/hip_runtime.h>
#include <hip/hip_bf16.h>
#include <stdint.h>

#define BB 32
#define NN 1024
#define MM 1024
#define DD 256

typedef __attribute__((ext_vector_type(8))) short short8;
typedef __attribute__((ext_vector_type(4))) float floatx4;

__device__ inline unsigned short f2bf(float x) {
    union { __hip_bfloat16 h; unsigned short u; } cv;
    cv.h = __float2bfloat16(x);
    return cv.u;
}
__device__ inline short8 pack8(float4 a, float4 b) {
    short8 o;
    o[0] = f2bf(a.x); o[1] = f2bf(a.y); o[2] = f2bf(a.z); o[3] = f2bf(a.w);
    o[4] = f2bf(b.x); o[5] = f2bf(b.y); o[6] = f2bf(b.z); o[7] = f2bf(b.w);
    return o;
}
// async global->LDS. LDS dest = wave-uniform base; HW adds lane*size.
__device__ inline void async_copy16(void* lds, const void* g) {
    __builtin_amdgcn_global_load_lds(
        (const __attribute__((address_space(1))) unsigned int*)g,
        (__attribute__((address_space(3))) unsigned int*)lds, 16, 0, 0);
}
__device__ inline void async_copy4(void* lds, const void* g) {
    __builtin_amdgcn_global_load_lds(
        (const __attribute__((address_space(1))) unsigned int*)g,
        (__attribute__((address_space(3))) unsigned int*)lds, 4, 0, 0);
}

// ---------------------------------------------------------------------------
// Convert h2 ONLY: fp32 -> bf16 + per-row sum of squares (fp32 exact),
// plus rowmin/colmin init folded in. One wave per TWO rows (32 B/lane).
// ---------------------------------------------------------------------------
__global__ __launch_bounds__(256) void convert_kernel(
        const float* __restrict__ h2, unsigned short* __restrict__ h2b,
        float* __restrict__ sq2, unsigned int* __restrict__ minb) {
    int g = blockIdx.x * 256 + threadIdx.x;
    if (g < 2 * BB * NN) minb[g] = 0x7F800000u;   // +inf

    int wid  = blockIdx.x * 4 + (threadIdx.x >> 6);
    int lane = threadIdx.x & 63;
    int l5   = lane & 31;
    int row  = wid * 2 + (lane >> 5);

    const float4* p = (const float4*)(h2 + (size_t)row * DD) + l5 * 2;
    float4 a = p[0], c = p[1];

    float s = a.x*a.x + a.y*a.y + a.z*a.z + a.w*a.w
            + c.x*c.x + c.y*c.y + c.z*c.z + c.w*c.w;
    #pragma unroll
    for (int off = 16; off; off >>= 1) s += __shfl_xor(s, off, 64);

    *(short8*)((char*)(h2b + (size_t)row * DD) + l5 * 16) = pack8(a, c);
    if (l5 == 0) sq2[row] = s;
}

// ---------------------------------------------------------------------------
// r8-identical A-resident GEMM + fused Hausdorff; A imported via
// REGISTER-staged pack (no LDS staging, no inter-quarter barriers):
// each thread loads a 64 B span of 4 h1 rows (fully coalesced, all in
// flight at once), packs to the bf16 PANEL in r8's swizzled layout,
// sq1 as by-product. Then r8 verbatim: unconditional af extraction
// (PANEL overwritten by ring bufs 2/3 -> af forced register-resident),
// 16 KB B chunks ring-4, ONE barrier/step, counted vmcnt 4/2/0,
// zero non-stage in-loop vmem.
// ---------------------------------------------------------------------------
__global__ __launch_bounds__(512, 2) void gemm_kernel(
        const float* __restrict__ h1, const unsigned short* __restrict__ h2b,
        const float* __restrict__ sq2,
        unsigned int* __restrict__ rowmin, unsigned int* __restrict__ colmin) {
    __shared__ __align__(16) char pool[98304];
    // [0,64K): bf16 A PANEL (prologue) -> B-bufs 2,3.  [64K,96K): B-bufs 0,1
    #define PANEL (pool)
    #define BUF0  (pool + 65536)
    #define BUF1  (pool + 81920)
    #define BUF2  (pool + 0)
    #define BUF3  (pool + 16384)
    __shared__ __align__(16) float  sq1_s[128];
    __shared__ __align__(16) float  sq2_s[1024];
    __shared__ unsigned int cl_s[1024];

    const int b    = blockIdx.x;       // batch; XCD = b%8
    const int tile = blockIdx.y;       // n-tile 0..7
    const int n0   = tile * 128;

    const int tid  = threadIdx.x;
    const int wave = tid >> 6;         // 0..7
    const int lane = tid & 63;
    const int wn   = (wave >> 2) * 64;     // {0,64}
    const int wm   = (wave & 3) * 32;      // {0,32,64,96}

    const char* Ag = (const char*)(h1 + ((size_t)b * NN + n0) * DD);  // 1KB rows
    const char* Bg = (const char*)(h2b + (size_t)b * MM * DD);        // 512B rows

    const int krow = lane >> 4;   // 0..3
    const int rrow = lane & 15;   // 0..15
    const int rx   = rrow & 7;
    const int lrow = krow * 4;
    const int lcol = rrow;

    // colmin LDS init (plain stores; drained before first use)
    cl_s[tid] = 0x7F800000u; cl_s[tid + 512] = 0x7F800000u;

    // ---- prologue: sq2 -> LDS ----
    #pragma unroll
    for (int t = 0; t < 2; ++t)
        async_copy4((char*)sq2_s + t * 2048 + wave * 256,
                    (const char*)(sq2 + b * MM) + t * 2048 + wave * 256 + lane * 4);

    // ---- A import: reg-staged, 4 quarters, no barriers ----
    const int prow = tid >> 4;      // 0..31 (row within quarter)
    const int pcol = tid & 15;      // 64 B col span
    float4 fa[4][4];
    #pragma unroll
    for (int q = 0; q < 4; ++q) {
        const char* rp = Ag + (size_t)(q * 32 + prow) * 1024 + pcol * 64;
        #pragma unroll
        for (int t = 0; t < 4; ++t) fa[q][t] = *(const float4*)(rp + t * 16);
    }

    // B stages issued now: newer than fa loads -> pack's compiler wait
    // (for fa) leaves these in flight.
    const int rl  = lane >> 3;
    const int bcu = (lane & 7) ^ rl;
    #define STAGE(mt_, ks_, BUFP)                                             \
        {                                                                     \
            _Pragma("unroll")                                                 \
            for (int c = 0; c < 2; ++c) {                                     \
                int ch_ = wave * 2 + c;                                       \
                int r_  = ch_ * 8 + rl;                                       \
                async_copy16((char*)(BUFP) + ch_ * 1024,                      \
                             Bg + (size_t)((mt_) * 128 + r_) * 512            \
                                + (size_t)(ks_) * 128 + (bcu << 4));          \
            }                                                                 \
        }

    STAGE(0, 0, BUF0);
    STAGE(0, 1, BUF1);

    // pack fa -> PANEL (r8's swizzled layout) + sq1 by-product
    {
        float sum = 0.f;
        #pragma unroll
        for (int q = 0; q < 4; ++q) {
            int rg = q * 32 + prow;
            #pragma unroll
            for (int jj = 0; jj < 2; ++jj) {
                float4 f0 = fa[q][jj * 2], f1 = fa[q][jj * 2 + 1];
                sum += f0.x*f0.x + f0.y*f0.y + f0.z*f0.z + f0.w*f0.w
                     + f1.x*f1.x + f1.y*f1.y + f1.z*f1.z + f1.w*f1.w;
                int ub = pcol * 2 + jj;
                *(short8*)(PANEL + (size_t)rg * 512 + ((ub ^ (rg & 7)) << 4))
                    = pack8(f0, f1);
            }
            // per-quarter row norm: reduce across the row's 16 threads
            float s = sum;
            s += __shfl_xor(s, 1, 64);
            s += __shfl_xor(s, 2, 64);
            s += __shfl_xor(s, 4, 64);
            s += __shfl_xor(s, 8, 64);
            if (pcol == 0) sq1_s[rg] = s;
            sum = 0.f;
        }
    }
    asm volatile("s_waitcnt lgkmcnt(0)" ::: "memory");
    __builtin_amdgcn_sched_barrier(0);
    __builtin_amdgcn_s_barrier();
    __builtin_amdgcn_sched_barrier(0);

    // ---- af extraction: r8-identical, unconditional, all waves ----
    short8 af[4][8];
    #pragma unroll
    for (int i = 0; i < 4; ++i) {
        #pragma unroll
        for (int kq = 0; kq < 8; ++kq) {
            int u = (kq * 4 + krow) ^ rx;
            af[i][kq] = *(const short8*)(PANEL
                        + (size_t)(wn + i * 16 + rrow) * 512 + (u << 4));
        }
    }
    asm volatile("s_waitcnt lgkmcnt(0)" ::: "memory");
    __builtin_amdgcn_sched_barrier(0);
    __builtin_amdgcn_s_barrier();
    __builtin_amdgcn_sched_barrier(0);
    // A region now dead -> BUF2/3 usable
    STAGE(0, 2, BUF2);

    float rmin[4][4];
    #pragma unroll
    for (int i = 0; i < 4; ++i)
        #pragma unroll
        for (int r = 0; r < 4; ++r) rmin[i][r] = 3.0e38f;

    // ---- main loop: 8 mt x 4 ks; ring = step % 4 (r8 verbatim) ----
    #pragma unroll 1
    for (int mt = 0; mt < 8; ++mt) {
        floatx4 acc[4][2] = {};

        #pragma unroll
        for (int ks = 0; ks < 4; ++ks) {
            if (mt == 7 && ks == 2)      { asm volatile("s_waitcnt vmcnt(2)" ::: "memory"); }
            else if (mt == 7 && ks == 3) { asm volatile("s_waitcnt vmcnt(0)" ::: "memory"); }
            else                         { asm volatile("s_waitcnt vmcnt(4)" ::: "memory"); }
            __builtin_amdgcn_s_barrier();
            __builtin_amdgcn_sched_barrier(0);

            if (ks == 0)          { STAGE(mt,     3, BUF3); }
            else if (mt < 7) {
                if (ks == 1)      { STAGE(mt + 1, 0, BUF0); }
                else if (ks == 2) { STAGE(mt + 1, 1, BUF1); }
                else              { STAGE(mt + 1, 2, BUF2); }
            }

            const char* Bb = (ks == 0) ? BUF0 : (ks == 1) ? BUF1
                           : (ks == 2) ? BUF2 : BUF3;
            __builtin_amdgcn_s_setprio(1);
            #pragma unroll
            for (int kk = 0; kk < 2; ++kk) {
                const int u = ((kk << 2) | krow) ^ rx;
                short8 bfv[2];
                #pragma unroll
                for (int j = 0; j < 2; ++j)
                    bfv[j] = *(const short8*)(Bb
                             + (size_t)(wm + j * 16 + rrow) * 128 + (u << 4));
                #pragma unroll
                for (int i = 0; i < 4; ++i)
                    #pragma unroll
                    for (int j = 0; j < 2; ++j)
                        acc[i][j] = __builtin_amdgcn_mfma_f32_16x16x32_bf16(
                            af[i][ks * 2 + kk], bfv[j], acc[i][j], 0, 0, 0);
            }
            __builtin_amdgcn_s_setprio(0);
        }

        // ---- per-mt epilogue: regs + LDS only (no vmem!) ----
        float s2v0 = sq2_s[mt * 128 + wm + lcol];
        float s2v1 = sq2_s[mt * 128 + wm + 16 + lcol];

        float cmin0 = 3.0e38f, cmin1 = 3.0e38f;
        #pragma unroll
        for (int i = 0; i < 4; ++i) {
            float4 s1q = *(const float4*)(&sq1_s[wn + i * 16 + lrow]);
            #pragma unroll
            for (int r = 0; r < 4; ++r) {
                float s1x = ((const float*)&s1q)[r];
                float d0 = fmaxf(s1x + s2v0 - 2.0f * acc[i][0][r], 0.0f);
                float d1 = fmaxf(s1x + s2v1 - 2.0f * acc[i][1][r], 0.0f);
                rmin[i][r] = fminf(rmin[i][r], fminf(d0, d1));
                cmin0 = fminf(cmin0, d0);
                cmin1 = fminf(cmin1, d1);
            }
        }
        cmin0 = fminf(cmin0, __shfl_xor(cmin0, 16, 64));
        cmin0 = fminf(cmin0, __shfl_xor(cmin0, 32, 64));
        cmin1 = fminf(cmin1, __shfl_xor(cmin1, 16, 64));
        cmin1 = fminf(cmin1, __shfl_xor(cmin1, 32, 64));
        if (lane < 16) {
            atomicMin(&cl_s[mt * 128 + wm + lcol],      __float_as_uint(cmin0));
            atomicMin(&cl_s[mt * 128 + wm + 16 + lcol], __float_as_uint(cmin1));
        }
    }

    // ---- final rowmin (global atomics, out of loop) ----
    unsigned int* rm = rowmin + b * NN + n0;
    #pragma unroll
    for (int i = 0; i < 4; ++i) {
        #pragma unroll
        for (int r = 0; r < 4; ++r) {
            float v = rmin[i][r];
            #pragma unroll
            for (int off = 1; off < 16; off <<= 1)
                v = fminf(v, __shfl_xor(v, off, 64));
            if (lcol == 0)
                atomicMin(&rm[wn + i * 16 + lrow + r], __float_as_uint(v));
        }
    }

    // ---- colmin flush: LDS -> global (once) ----
    __syncthreads();
    unsigned int* cmg = colmin + b * MM;
    atomicMin(&cmg[tid],       cl_s[tid]);
    atomicMin(&cmg[tid + 512], cl_s[tid + 512]);
    #undef STAGE
    #undef PANEL
    #undef BUF0
    #undef BUF1
    #undef BUF2
    #undef BUF3
}

// ---------------------------------------------------------------------------
__global__ __launch_bounds__(256) void finalize_kernel(
        const unsigned int* __restrict__ rowmin,
        const unsigned int* __restrict__ colmin,
        float* __restrict__ out) {
    int b = blockIdx.x;
    int tid = threadIdx.x;
    float s = 0.0f;
    for (int i = tid; i < NN; i += 256) s += __uint_as_float(rowmin[b * NN + i]);
    for (int i = tid; i < MM; i += 256) s += __uint_as_float(colmin[b * MM + i]);
    #pragma unroll
    for (int off = 32; off; off >>= 1) s += __shfl_xor(s, off, 64);
    __shared__ float wsum[4];
    if ((tid & 63) == 0) wsum[tid >> 6] = s;
    __syncthreads();
    if (tid == 0) out[b] = (wsum[0] + wsum[1] + wsum[2] + wsum[3]) * (1.0f / 1024.0f);
}

// ---------------------------------------------------------------------------
extern "C" void kernel_launch(void* const* d_in, const int* in_sizes, int n_in,
                              void* d_out, int out_size, void* d_ws, size_t ws_size,
                              hipStream_t stream) {
    const float* h1 = (const float*)d_in[0];
    const float* h2 = (const float*)d_in[1];
    float* out = (float*)d_out;

    char* ws = (char*)d_ws;
    unsigned short* h2b = (unsigned short*)ws;                    // 16 MB
    float* sq2          = (float*)(ws + (size_t)BB * MM * DD * 2);
    unsigned int* rowmin = (unsigned int*)(sq2 + BB * MM);        // 128 KB
    unsigned int* colmin = rowmin + BB * NN;                      // 128 KB

    // h2 convert + norms + min-buffer init (rowmin/colmin contiguous)
    hipLaunchKernelGGL(convert_kernel, dim3(4096), dim3(256), 0, stream,
                       h2, h2b, sq2, rowmin);

    hipLaunchKernelGGL(gemm_kernel, dim3(BB, 8), dim3(512), 0, stream,
                       h1, h2b, sq2, rowmin, colmin);

    hipLaunchKernelGGL(finalize_kernel, dim3(BB), dim3(256), 0, stream,
                       rowmin, colmin, out);
}